// Round 9
// baseline (255.388 us; speedup 1.0000x reference)
//
#include <hip/hip_runtime.h>
#include <math.h>
#include <stdio.h>

#define N_NODES 51200
#define N_EDGES 409600
#define B_GRAPH 256
#define NH 13

typedef float v4f __attribute__((ext_vector_type(4)));
typedef short s16x8 __attribute__((ext_vector_type(8)));   // 8 bf16 = 4 VGPR (MFMA A/B frag)
typedef float f32x4 __attribute__((ext_vector_type(4)));   // MFMA C/D frag

// bf16 pack (RNE) / unpack helpers.
__device__ __forceinline__ unsigned pack_bf2(float a, float b) {
    unsigned ua = __float_as_uint(a);
    ua = (ua + 0x7fffu + ((ua >> 16) & 1u)) >> 16;
    unsigned ub = __float_as_uint(b);
    ub = (ub + 0x7fffu + ((ub >> 16) & 1u)) & 0xffff0000u;
    return ua | ub;
}
__device__ __forceinline__ float bf_lo(unsigned u) { return __uint_as_float(u << 16); }
__device__ __forceinline__ float bf_hi(unsigned u) { return __uint_as_float(u & 0xffff0000u); }

__device__ __forceinline__ s16x8 as_s8(uint4 u) {
    return __builtin_bit_cast(s16x8, u);
}
__device__ __forceinline__ f32x4 mfma16(s16x8 a, s16x8 b, f32x4 c) {
    return __builtin_amdgcn_mfma_f32_16x16x32_bf16(a, b, c, 0, 0, 0);
}

// Split 8 fp32 (two float4 = frag elems e0..3, e4..7) into hi/lo bf16 frags.
__device__ __forceinline__ void cvt_hilo(const float4& xa, const float4& xb,
                                         s16x8& hi, s16x8& lo) {
    unsigned h0 = pack_bf2(xa.x, xa.y);
    unsigned h1 = pack_bf2(xa.z, xa.w);
    unsigned h2 = pack_bf2(xb.x, xb.y);
    unsigned h3 = pack_bf2(xb.z, xb.w);
    unsigned l0 = pack_bf2(xa.x - bf_lo(h0), xa.y - bf_hi(h0));
    unsigned l1 = pack_bf2(xa.z - bf_lo(h1), xa.w - bf_hi(h1));
    unsigned l2 = pack_bf2(xb.x - bf_lo(h2), xb.y - bf_hi(h2));
    unsigned l3 = pack_bf2(xb.z - bf_lo(h3), xb.w - bf_hi(h3));
    hi = as_s8(make_uint4(h0, h1, h2, h3));
    lo = as_s8(make_uint4(l0, l1, l2, l3));
}

// ei dtype probe, inlined: int64 ei has zero high words (uniform scalar loads).
__device__ __forceinline__ bool ei_is_64(const int* __restrict__ ei32) {
    int z = 1;
    #pragma unroll
    for (int k = 1; k < 16; k += 2) z &= (ei32[k] == 0);
    return z != 0;
}

// count_deg (per-node atomics, 51200 counters -> ~8/addr, uncontended) +
// fused W1/W2 hi/lo MFMA-fragment prep (blocks >= 1600).
__global__ void count_deg(const int* __restrict__ ei32, const long long* __restrict__ ei64,
                          int* __restrict__ degc,
                          const float* __restrict__ W1, const float* __restrict__ W2,
                          uint4* __restrict__ w1h, uint4* __restrict__ w1l,
                          uint4* __restrict__ w2h, uint4* __restrict__ w2l) {
    const int bid = blockIdx.x;
    if (bid >= 1600) {
        int rec = (bid - 1600) * 256 + threadIdx.x;  // [0,4096)
        bool isW1 = rec < 2048;
        int r = isW1 ? rec : rec - 2048;
        int l = r & 63;
        int lg = l >> 4;
        int col, krow, N;
        const float* W;
        if (isW1) {  // 16 cfrag x 2 ks x 64 lanes
            int c = r >> 7; int s = (r >> 6) & 1;
            col = c * 16 + (l & 15); krow = s * 32 + lg * 4; W = W1; N = 256;
        } else {     // 4 cfrag x 8 ks x 64 lanes
            int c = r >> 9; int s = (r >> 6) & 7;
            col = c * 16 + (l & 15); krow = s * 32 + lg * 4; W = W2; N = 64;
        }
        float f[8];
        #pragma unroll
        for (int e = 0; e < 8; ++e) {
            int kk = krow + (e & 3) + 16 * (e >> 2);
            f[e] = W[(size_t)kk * N + col];
        }
        unsigned h[4], lo[4];
        #pragma unroll
        for (int p = 0; p < 4; ++p) {
            h[p] = pack_bf2(f[2 * p], f[2 * p + 1]);
            lo[p] = pack_bf2(f[2 * p] - bf_lo(h[p]), f[2 * p + 1] - bf_hi(h[p]));
        }
        uint4 H = make_uint4(h[0], h[1], h[2], h[3]);
        uint4 L = make_uint4(lo[0], lo[1], lo[2], lo[3]);
        if (isW1) { w1h[r] = H; w1l[r] = L; }
        else      { w2h[r] = H; w2l[r] = L; }
        return;
    }
    int e = bid * 256 + threadIdx.x;
    if (e >= N_EDGES) return;
    int v = ei_is_64(ei32) ? (int)__builtin_nontemporal_load(&ei64[N_EDGES + e])
                           : __builtin_nontemporal_load(&ei32[N_EDGES + e]);
    atomicAdd(&degc[v], 1);
}

__global__ void scan_block_sums(const int* __restrict__ degc, int* __restrict__ bsums) {
    __shared__ int sdata[256];
    int i = blockIdx.x * 256 + threadIdx.x;
    sdata[threadIdx.x] = degc[i];
    __syncthreads();
    for (int s = 128; s > 0; s >>= 1) {
        if (threadIdx.x < s) sdata[threadIdx.x] += sdata[threadIdx.x + s];
        __syncthreads();
    }
    if (threadIdx.x == 0) bsums[blockIdx.x] = sdata[0];
}

__global__ void scan_finalize(int* __restrict__ degc, int* __restrict__ offs,
                              float* __restrict__ dinv, const int* __restrict__ bsums) {
    __shared__ int bs[256];
    __shared__ int s[256];
    const int t = threadIdx.x;
    bs[t] = (t < 200) ? bsums[t] : 0;
    __syncthreads();
    for (int off = 1; off < 256; off <<= 1) {
        int u = (t >= off) ? bs[t - off] : 0;
        __syncthreads();
        bs[t] += u;
        __syncthreads();
    }
    int i = blockIdx.x * 256 + t;
    int cnt = degc[i];
    s[t] = cnt;
    __syncthreads();
    for (int off = 1; off < 256; off <<= 1) {
        int u = (t >= off) ? s[t - off] : 0;
        __syncthreads();
        s[t] += u;
        __syncthreads();
    }
    int base = (blockIdx.x == 0) ? 0 : bs[blockIdx.x - 1];
    int excl = base + s[t] - cnt;
    offs[i] = excl;
    dinv[i] = rsqrtf((float)(cnt + 1));
    degc[i] = excl;  // fill cursor
    if (i == N_NODES - 1) offs[N_NODES] = N_EDGES;
}

// ---- 64x64 tile body (af path): gather + bias, fp32 out, 4x4/thread ----
template <int K, int WS, bool BF16IN>
__device__ __forceinline__ void gemm_body64(const float* __restrict__ X,
        const float* __restrict__ W, const float* __restrict__ bias,
        float* __restrict__ Y, int row0, const int* __restrict__ rows,
        float* __restrict__ xs, float* __restrict__ ws) {
    constexpr int BK = 32;
    constexpr int XS = BK + 4;
    const int t = threadIdx.x;
    const int ct = t & 15;
    const int rt = t >> 4;
    float acc[4][4] = {{0.f}};
    for (int kc = 0; kc < K; kc += BK) {
        __syncthreads();
        #pragma unroll
        for (int i = 0; i < 2; ++i) {
            int idx = t + i * 256;
            int q = idx & 7, r = idx >> 3;
            int xr = rows[r];
            float4 v;
            if (BF16IN) {
                uint2 pv = ((const uint2*)X)[(size_t)xr * (K / 4) + kc / 4 + q];
                v = make_float4(bf_lo(pv.x), bf_hi(pv.x), bf_lo(pv.y), bf_hi(pv.y));
            } else {
                v = *(const float4*)(X + (size_t)xr * K + kc + q * 4);
            }
            *(float4*)&xs[r * XS + q * 4] = v;
        }
        #pragma unroll
        for (int i = 0; i < 2; ++i) {
            int idx = t + i * 256;
            int q = idx & 15, k = idx >> 4;
            float4 v = *(const float4*)(W + (size_t)(kc + k) * WS + q * 4);
            *(float4*)&ws[k * 64 + q * 4] = v;
        }
        __syncthreads();
        #pragma unroll
        for (int kb = 0; kb < BK; kb += 4) {
            float4 wv[4];
            #pragma unroll
            for (int kk = 0; kk < 4; ++kk)
                wv[kk] = *(const float4*)&ws[(kb + kk) * 64 + ct * 4];
            #pragma unroll
            for (int r = 0; r < 4; ++r) {
                float4 xv = *(const float4*)&xs[(rt * 4 + r) * XS + kb];
                float xk[4] = {xv.x, xv.y, xv.z, xv.w};
                #pragma unroll
                for (int kk = 0; kk < 4; ++kk) {
                    acc[r][0] = fmaf(xk[kk], wv[kk].x, acc[r][0]);
                    acc[r][1] = fmaf(xk[kk], wv[kk].y, acc[r][1]);
                    acc[r][2] = fmaf(xk[kk], wv[kk].z, acc[r][2]);
                    acc[r][3] = fmaf(xk[kk], wv[kk].w, acc[r][3]);
                }
            }
        }
    }
    #pragma unroll
    for (int r = 0; r < 4; ++r) {
        int row = row0 + rt * 4 + r;
        float4 o = make_float4(acc[r][0] + bias[ct * 4 + 0],
                               acc[r][1] + bias[ct * 4 + 1],
                               acc[r][2] + bias[ct * 4 + 2],
                               acc[r][3] + bias[ct * 4 + 3]);
        *(float4*)&Y[(size_t)row * 512 + ct * 4] = o;
    }
}

// ---- fused 1: [0,416) af0 (heaviest per-block: start first),
//      [416,3616) csr-fill (even parity) interleaved with gemm1 MFMA (odd). ----
__global__ __launch_bounds__(256, 4) void fused_gemm1(const float* __restrict__ x,
        const uint4* __restrict__ w1h, const uint4* __restrict__ w1l,
        float* __restrict__ xw1b, const float* __restrict__ dinv,
        const int* __restrict__ ei32, const long long* __restrict__ ei64,
        int* __restrict__ cursor, int* __restrict__ csr,
        const int* __restrict__ host_idx,
        const float* __restrict__ a0W, const float* __restrict__ a0b,
        const float* __restrict__ f0W, const float* __restrict__ f0b,
        float* __restrict__ AF) {
    __shared__ float smem[64 * 68];  // af scratch / gemm epilogue
    __shared__ int rows[64];
    const int bid = blockIdx.x;
    const int t = threadIdx.x;
    if (bid < 416) {
        const int rb = bid >> 3;
        const int cb = bid & 7;
        const int c0 = cb * 64;
        const float* Wp = (c0 < 256) ? (a0W + c0) : (f0W + (c0 - 256));
        const float* bp = (c0 < 256) ? (a0b + c0) : (f0b + (c0 - 256));
        if (t < 64) rows[t] = host_idx[rb * 64 + t];
        __syncthreads();
        gemm_body64<64, 256, false>(x, Wp, bp, AF + c0, rb * 64, rows, smem, smem + 64 * 36);
    } else if ((bid - 416) & 1) {
        const int gid = (bid - 416) >> 1;   // [0,1600)
        const int row0 = (gid % 400) * 128;
        const int c0 = (gid / 400) * 64;
        const int w = t >> 6, l = t & 63, lr = l & 15, lg = l >> 4;
        f32x4 acc[2][4] = {};
        #pragma unroll
        for (int s = 0; s < 2; ++s) {
            s16x8 bh[4], bl[4];
            #pragma unroll
            for (int cc = 0; cc < 4; ++cc) {
                int idx = (((c0 >> 4) + cc) * 2 + s) * 64 + l;
                bh[cc] = as_s8(w1h[idx]);
                bl[cc] = as_s8(w1l[idx]);
            }
            #pragma unroll
            for (int f = 0; f < 2; ++f) {
                int rowA = row0 + w * 32 + f * 16 + lr;
                const float* xp = x + (size_t)rowA * 64 + s * 32 + lg * 4;
                float4 xa = *(const float4*)xp;
                float4 xb = *(const float4*)(xp + 16);
                s16x8 ah, al;
                cvt_hilo(xa, xb, ah, al);
                #pragma unroll
                for (int cc = 0; cc < 4; ++cc) {
                    acc[f][cc] = mfma16(ah, bh[cc], acc[f][cc]);
                    acc[f][cc] = mfma16(al, bh[cc], acc[f][cc]);
                    acc[f][cc] = mfma16(ah, bl[cc], acc[f][cc]);
                }
            }
        }
        // epilogue: dinv prescale -> LDS transpose (2 slices of 64 rows) -> bf16 store
        #pragma unroll
        for (int f = 0; f < 2; ++f) {
            if (f) __syncthreads();
            #pragma unroll
            for (int r = 0; r < 4; ++r) {
                float dv = dinv[row0 + w * 32 + f * 16 + lg * 4 + r];
                #pragma unroll
                for (int cc = 0; cc < 4; ++cc)
                    smem[(w * 16 + lg * 4 + r) * 68 + cc * 16 + lr] = acc[f][cc][r] * dv;
            }
            __syncthreads();
            int row_l = t >> 2, cB = (t & 3) * 16;
            int grow = row0 + (row_l >> 4) * 32 + f * 16 + (row_l & 15);
            const float* src = &smem[row_l * 68 + cB];
            float4 v0 = *(const float4*)(src + 0);
            float4 v1 = *(const float4*)(src + 4);
            float4 v2 = *(const float4*)(src + 8);
            float4 v3 = *(const float4*)(src + 12);
            uint4 o0, o1;
            o0.x = pack_bf2(v0.x, v0.y); o0.y = pack_bf2(v0.z, v0.w);
            o0.z = pack_bf2(v1.x, v1.y); o0.w = pack_bf2(v1.z, v1.w);
            o1.x = pack_bf2(v2.x, v2.y); o1.y = pack_bf2(v2.z, v2.w);
            o1.z = pack_bf2(v3.x, v3.y); o1.w = pack_bf2(v3.z, v3.w);
            uint4* yp = (uint4*)xw1b + (size_t)grow * 32 + (c0 >> 3) + (t & 3) * 2;
            yp[0] = o0;
            yp[1] = o1;
        }
    } else {
        int e = ((bid - 416) >> 1) * 256 + t;   // [0,1600) blocks
        if (e < N_EDGES) {
            int u, v;
            if (ei_is_64(ei32)) {
                u = (int)__builtin_nontemporal_load(&ei64[e]);
                v = (int)__builtin_nontemporal_load(&ei64[N_EDGES + e]);
            } else {
                u = __builtin_nontemporal_load(&ei32[e]);
                v = __builtin_nontemporal_load(&ei32[N_EDGES + e]);
            }
            int pos = atomicAdd(&cursor[v], 1);
            csr[pos] = u;
        }
    }
}

// ---- fused 2 (af1 only now): 416 blocks, gather host rows of x1b ----
__global__ __launch_bounds__(256, 4) void fused_gemm2(const float* __restrict__ x1b,
        const int* __restrict__ host_idx,
        const float* __restrict__ a1W, const float* __restrict__ a1b,
        const float* __restrict__ f1W, const float* __restrict__ f1b,
        float* __restrict__ AF) {
    __shared__ float smem[64 * 68];
    __shared__ int rows[64];
    const int bid = blockIdx.x;
    const int t = threadIdx.x;
    const int rb = bid >> 3;
    const int cb = bid & 7;
    const int c0 = cb * 64;
    const float* Wp = (c0 < 256) ? (a1W + c0) : (f1W + (c0 - 256));
    const float* bp = (c0 < 256) ? (a1b + c0) : (f1b + (c0 - 256));
    if (t < 64) rows[t] = host_idx[rb * 64 + t];
    __syncthreads();
    gemm_body64<256, 256, true>(x1b, Wp, bp, AF + c0, rb * 64, rows, smem, smem + 64 * 36);
}

// ---- attn reduce body (H=256): softmax over feats + weighted sum + g update ----
__device__ __forceinline__ void attn_red256(const float* __restrict__ AF,
        const float* __restrict__ gW, const float* __restrict__ gb,
        const float* __restrict__ g_in, float* __restrict__ g_out, int b,
        float (*At)[256], float* red_m, float* red_s, float* cat) {
    const int t = threadIdx.x;
    const int wave = t >> 6, lane = t & 63;
    float accA[NH], accF[NH];
    #pragma unroll
    for (int j = 0; j < NH; ++j) {
        const float* r = AF + (size_t)(b * NH + j) * 512;
        accA[j] = r[t];
        accF[j] = r[256 + t];
        At[j][t] = accA[j];
    }
    __syncthreads();
    for (int j = wave; j < NH; j += 4) {
        float m = -3.402823466e38f;
        #pragma unroll
        for (int q = 0; q < 4; ++q) m = fmaxf(m, At[j][q * 64 + lane]);
        #pragma unroll
        for (int off = 32; off; off >>= 1) m = fmaxf(m, __shfl_xor(m, off));
        if (lane == 0) red_m[j] = m;
    }
    __syncthreads();
    #pragma unroll
    for (int j = 0; j < NH; ++j) At[j][t] = expf(accA[j] - red_m[j]);
    __syncthreads();
    for (int j = wave; j < NH; j += 4) {
        float s = 0.f;
        #pragma unroll
        for (int q = 0; q < 4; ++q) s += At[j][q * 64 + lane];
        #pragma unroll
        for (int off = 32; off; off >>= 1) s += __shfl_xor(s, off);
        if (lane == 0) red_s[j] = s;
    }
    __syncthreads();
    float outc = 0.f;
    #pragma unroll
    for (int j = 0; j < NH; ++j) outc += At[j][t] / red_s[j] * accF[j];
    cat[t] = outc;
    float gv = g_in ? g_in[b * 256 + t] : 0.f;
    cat[256 + t] = gv;
    __syncthreads();
    float acc = gb[t];
    const float* gwp = gW + t;
    #pragma unroll 4
    for (int i4 = 0; i4 < 128; ++i4) {
        float4 cq = ((const float4*)cat)[i4];
        const float* gw4 = gwp + (size_t)i4 * 4 * 256;
        acc = fmaf(cq.x, gw4[0], acc);
        acc = fmaf(cq.y, gw4[256], acc);
        acc = fmaf(cq.z, gw4[512], acc);
        acc = fmaf(cq.w, gw4[768], acc);
    }
    g_out[b * 256 + t] = gv + acc;
}

// ---- fused: [0,256) attn reduce 0, [256,6912) agg_max + FUSED gemm2:
//      block handles 8 v (one per half-wave, round-6 proven shape, 8 uint4
//      in flight); relu'd bf16 rows -> LDS rows 0-7 (stride 132, rows 8-15
//      zeroed); host rows also -> x1b. Then 4 waves compute
//      xw2[8 rows][16 cols each] via MFMA w2 hi/lo (zero rows unstored).
//      8v/block doubles grid depth (26 blk/CU) for finer drain/tail. ----
__global__ __launch_bounds__(256) void fused_agg256(const uint4* __restrict__ xwb4,
        const float* __restrict__ dinv, const int* __restrict__ offs,
        const int* __restrict__ csr, const float* __restrict__ bias,
        uint4* __restrict__ x1b_host,
        const uint4* __restrict__ w2h, const uint4* __restrict__ w2l,
        float* __restrict__ xw2,
        const float* __restrict__ AF, const float* __restrict__ gW,
        const float* __restrict__ gb, const float* __restrict__ g_in,
        float* __restrict__ g_out) {
    __shared__ __align__(16) float At[NH][256];   // 13312 B; gather path overlays x1s
    __shared__ float red_m[NH];
    __shared__ float red_s[NH];
    __shared__ float cat[512];
    const int bid = blockIdx.x;
    if (bid < 256) {
        attn_red256(AF, gW, gb, g_in, g_out, bid, At, red_m, red_s, cat);
        return;
    }
    unsigned* x1s = (unsigned*)At;              // [16][132] uints (8448 B)
    const int t = threadIdx.x;
    const int v0 = (bid - 256) * 8;
    const int hw = t >> 5;                      // half-wave 0..7
    const int cl = t & 31;                      // uint4 chunk in row
    // zero rows 8..15 (A-frag padding for the MFMA phase)
    for (int i = t; i < 8 * 132; i += 256) x1s[8 * 132 + i] = 0;
    {
        const int v = v0 + hw;                  // one v per half-wave
        uint4 sw = xwb4[(size_t)v * 32 + cl];   // self row (pre-scaled bf16)
        float acc[8];
        acc[0] = bf_lo(sw.x); acc[1] = bf_hi(sw.x);
        acc[2] = bf_lo(sw.y); acc[3] = bf_hi(sw.y);
        acc[4] = bf_lo(sw.z); acc[5] = bf_hi(sw.z);
        acc[6] = bf_lo(sw.w); acc[7] = bf_hi(sw.w);
        const int e0 = offs[v];
        const int e1 = offs[v + 1];
        const int em = e0 + ((e1 - e0) & ~7);
        for (int e = e0; e < em; e += 8) {      // 8 edges in flight
            int u[8];
            #pragma unroll
            for (int i = 0; i < 8; ++i) u[i] = csr[e + i];
            uint4 m[8];
            #pragma unroll
            for (int i = 0; i < 8; ++i) m[i] = xwb4[(size_t)u[i] * 32 + cl];
            #pragma unroll
            for (int i = 0; i < 8; ++i) {
                acc[0] = fmaxf(acc[0], bf_lo(m[i].x)); acc[1] = fmaxf(acc[1], bf_hi(m[i].x));
                acc[2] = fmaxf(acc[2], bf_lo(m[i].y)); acc[3] = fmaxf(acc[3], bf_hi(m[i].y));
                acc[4] = fmaxf(acc[4], bf_lo(m[i].z)); acc[5] = fmaxf(acc[5], bf_hi(m[i].z));
                acc[6] = fmaxf(acc[6], bf_lo(m[i].w)); acc[7] = fmaxf(acc[7], bf_hi(m[i].w));
            }
        }
        if (em < e1) {                          // tail <8 edges, clamped
            int u[8];
            #pragma unroll
            for (int i = 0; i < 8; ++i) {
                int idx = em + i;
                u[i] = csr[(idx < e1) ? idx : (e1 - 1)];
            }
            uint4 m[8];
            #pragma unroll
            for (int i = 0; i < 8; ++i) m[i] = xwb4[(size_t)u[i] * 32 + cl];
            #pragma unroll
            for (int i = 0; i < 8; ++i) {
                acc[0] = fmaxf(acc[0], bf_lo(m[i].x)); acc[1] = fmaxf(acc[1], bf_hi(m[i].x));
                acc[2] = fmaxf(acc[2], bf_lo(m[i].y)); acc[3] = fmaxf(acc[3], bf_hi(m[i].y));
                acc[4] = fmaxf(acc[4], bf_lo(m[i].z)); acc[5] = fmaxf(acc[5], bf_hi(m[i].z));
                acc[6] = fmaxf(acc[6], bf_lo(m[i].w)); acc[7] = fmaxf(acc[7], bf_hi(m[i].w));
            }
        }
        float dv = dinv[v];
        float4 ba = ((const float4*)bias)[cl * 2];
        float4 bb = ((const float4*)bias)[cl * 2 + 1];
        uint4 pk;
        pk.x = pack_bf2(fmaxf(fmaf(acc[0], dv, ba.x), 0.f),
                        fmaxf(fmaf(acc[1], dv, ba.y), 0.f));
        pk.y = pack_bf2(fmaxf(fmaf(acc[2], dv, ba.z), 0.f),
                        fmaxf(fmaf(acc[3], dv, ba.w), 0.f));
        pk.z = pack_bf2(fmaxf(fmaf(acc[4], dv, bb.x), 0.f),
                        fmaxf(fmaf(acc[5], dv, bb.y), 0.f));
        pk.w = pack_bf2(fmaxf(fmaf(acc[6], dv, bb.z), 0.f),
                        fmaxf(fmaf(acc[7], dv, bb.w), 0.f));
        *(uint4*)&x1s[hw * 132 + cl * 4] = pk;  // LDS row for MFMA phase
        if (v % 200 < NH)                       // host row -> af1 input
            x1b_host[(size_t)v * 32 + cl] = pk;
    }
    __syncthreads();
    // MFMA phase: wave wv computes cols [wv*16, wv*16+16) of xw2 for rows 0-7
    // (A-frag rows 8-15 are zeros; their outputs are discarded).
    {
        const int wv = t >> 6, l = t & 63;
        const int ra = l & 15, lg = l >> 4;
        f32x4 acc2 = {};
        #pragma unroll
        for (int s = 0; s < 8; ++s) {
            s16x8 bh = as_s8(((const uint4*)w2h)[(wv * 8 + s) * 64 + l]);
            s16x8 bl = as_s8(((const uint4*)w2l)[(wv * 8 + s) * 64 + l]);
            const unsigned* ap = &x1s[ra * 132 + s * 16 + lg * 2];
            s16x8 a = as_s8(make_uint4(ap[0], ap[1], ap[8], ap[9]));
            acc2 = mfma16(a, bh, acc2);
            acc2 = mfma16(a, bl, acc2);
        }
        #pragma unroll
        for (int e = 0; e < 4; ++e) {
            int row = lg * 4 + e;
            if (row < 8)
                xw2[(size_t)(v0 + row) * 64 + wv * 16 + ra] = acc2[e] * dinv[v0 + row];
        }
    }
}

// ---- per-graph mega-kernel, 1024 threads (verified round 13) ----
__global__ __launch_bounds__(1024) void attn_graph_head(
        const float* __restrict__ AF,
        const float* __restrict__ g1W, const float* __restrict__ g1b,
        const float* __restrict__ g_in,
        const float* __restrict__ xw2,
        const float* __restrict__ dinv, const int* __restrict__ offs,
        const int* __restrict__ csr, const float* __restrict__ b2,
        const int* __restrict__ host_idx,
        const float* __restrict__ a2W, const float* __restrict__ a2b,
        const float* __restrict__ f2W, const float* __restrict__ f2b,
        const float* __restrict__ g2W, const float* __restrict__ g2b,
        const float* __restrict__ o1W, const float* __restrict__ o1b,
        const float* __restrict__ o2W, const float* __restrict__ o2b,
        float* __restrict__ out) {
    __shared__ float At[NH][256];
    __shared__ float Ft[NH][256];
    __shared__ float red_m[NH];
    __shared__ float red_s[NH];
    __shared__ float cat[512];
    __shared__ float catB[320];
    __shared__ float g1s[256];
    __shared__ float x2l[NH][64];
    __shared__ float part4[4][256];
    __shared__ float part16[16][64];
    __shared__ float grow[256];
    const int b = blockIdx.x;
    const int t = threadIdx.x;
    const int wave = t >> 6;
    const int lane = t & 63;
    const int c = t & 255;
    const int quad = t >> 8;

    if (wave < NH) {
        int hv = host_idx[b * NH + wave];
        float acc = xw2[(size_t)hv * 64 + lane];
        int e0 = offs[hv], e1 = offs[hv + 1];
        for (int e = e0; e < e1; e += 8) {
            int u[8];
            #pragma unroll
            for (int i = 0; i < 8; ++i) u[i] = csr[(e + i < e1) ? (e + i) : (e1 - 1)];
            float m[8];
            #pragma unroll
            for (int i = 0; i < 8; ++i) m[i] = xw2[(size_t)u[i] * 64 + lane];
            #pragma unroll
            for (int i = 0; i < 8; ++i)
                if (e + i < e1) acc = fmaxf(acc, m[i]);
        }
        x2l[wave][lane] = fmaxf(fmaf(acc, dinv[hv], b2[lane]), 0.f);
    }
    for (int idx = t; idx < NH * 128; idx += 1024) {
        int j = idx >> 7, q = idx & 127;
        float4 v = ((const float4*)(AF + (size_t)(b * NH + j) * 512))[q];
        if (q < 64) *(float4*)&At[j][q * 4] = v;
        else        *(float4*)&Ft[j][(q - 64) * 4] = v;
    }
    __syncthreads();
    if (wave < NH) {
        float m = -3.402823466e38f;
        #pragma unroll
        for (int q = 0; q < 4; ++q) m = fmaxf(m, At[wave][q * 64 + lane]);
        #pragma unroll
        for (int off = 32; off; off >>= 1) m = fmaxf(m, __shfl_xor(m, off));
        if (lane == 0) red_m[wave] = m;
    }
    __syncthreads();
    for (int idx = t; idx < NH * 256; idx += 1024) {
        int j = idx >> 8, cc = idx & 255;
        At[j][cc] = expf(At[j][cc] - red_m[j]);
    }
    __syncthreads();
    if (wave < NH) {
        float s = 0.f;
        #pragma unroll
        for (int q = 0; q < 4; ++q) s += At[wave][q * 64 + lane];
        #pragma unroll
        for (int off = 32; off; off >>= 1) s += __shfl_xor(s, off);
        if (lane == 0) red_s[wave] = s;
    }
    __syncthreads();
    if (quad == 0) {
        float outc = 0.f;
        #pragma unroll
        for (int j = 0; j < NH; ++j) outc += At[j][c] / red_s[j] * Ft[j][c];
        cat[c] = outc;
        cat[256 + c] = g_in[b * 256 + c];
    }
    __syncthreads();
    // g1W update: 512 floats = 128 float4, 32 per quad (full coverage)
    {
        float acc = 0.f;
        const float* gwp = g1W + c;
        #pragma unroll 4
        for (int i4 = quad * 32; i4 < quad * 32 + 32; ++i4) {
            float4 cq = ((const float4*)cat)[i4];
            const float* gw4 = gwp + (size_t)i4 * 1024;
            acc = fmaf(cq.x, gw4[0], acc);
            acc = fmaf(cq.y, gw4[256], acc);
            acc = fmaf(cq.z, gw4[512], acc);
            acc = fmaf(cq.w, gw4[768], acc);
        }
        part4[quad][c] = acc;
    }
    __syncthreads();
    if (quad == 0)
        g1s[c] = cat[256 + c] + g1b[c] +
                 part4[0][c] + part4[1][c] + part4[2][c] + part4[3][c];
    __syncthreads();
    if (wave < NH) {
        float aA = a2b[lane], aF = f2b[lane];
        #pragma unroll 8
        for (int k = 0; k < 64; ++k) {
            float xv = x2l[wave][k];
            aA = fmaf(xv, a2W[k * 64 + lane], aA);
            aF = fmaf(xv, f2W[k * 64 + lane], aF);
        }
        float m = aA;
        #pragma unroll
        for (int off = 32; off; off >>= 1) m = fmaxf(m, __shfl_xor(m, off));
        float pexp = expf(aA - m);
        float s = pexp;
        #pragma unroll
        for (int off = 32; off; off >>= 1) s += __shfl_xor(s, off);
        At[wave][lane] = pexp / s * aF;
    }
    __syncthreads();
    if (t < 64) {
        float o = 0.f;
        #pragma unroll
        for (int j = 0; j < NH; ++j) o += At[j][t];
        catB[t] = o;
    }
    if (quad == 0) catB[64 + c] = g1s[c];
    __syncthreads();
    // g2W update: 320 floats = 80 float4, 20 per quad
    {
        float acc = 0.f;
        const float* gwp = g2W + c;
        #pragma unroll 4
        for (int i4 = quad * 20; i4 < quad * 20 + 20; ++i4) {
            float4 cq = ((const float4*)catB)[i4];
            const float* gw4 = gwp + (size_t)i4 * 1024;
            acc = fmaf(cq.x, gw4[0], acc);
            acc = fmaf(cq.y, gw4[256], acc);
            acc = fmaf(cq.z, gw4[512], acc);
            acc = fmaf(cq.w, gw4[768], acc);
        }
        part4[quad][c] = acc;
    }
    __syncthreads();
    if (quad == 0)
        grow[c] = g1s[c] + g2b[c] +
                  part4[0][c] + part4[1][c] + part4[2][c] + part4[3][c];
    __syncthreads();
    {
        float hp = 0.f;
        #pragma unroll
        for (int k = wave * 16; k < wave * 16 + 16; ++k)
            hp = fmaf(grow[k], o1W[(size_t)k * 64 + lane], hp);
        part16[wave][lane] = hp;
    }
    __syncthreads();
    if (wave == 0) {
        float h = o1b[lane];
        #pragma unroll
        for (int w = 0; w < 16; ++w) h += part16[w][lane];
        h = fmaxf(h, 0.f);
        float sres = h * o2W[lane];
        #pragma unroll
        for (int off = 32; off; off >>= 1) sres += __shfl_xor(sres, off);
        if (lane == 0) out[b] = sres + o2b[0];
    }
}

extern "C" void kernel_launch(void* const* d_in, const int* in_sizes, int n_in,
                              void* d_out, int out_size, void* d_ws, size_t ws_size,
                              hipStream_t stream) {
    (void)in_sizes; (void)n_in; (void)out_size;
    const float* x    = (const float*)d_in[0];
    const int* ei32   = (const int*)d_in[1];
    const long long* ei64 = (const long long*)d_in[1];
    const int* hidx   = (const int*)d_in[2];
    const float* W1 = (const float*)d_in[3],  *b1 = (const float*)d_in[4];
    const float* W2 = (const float*)d_in[5],  *b2 = (const float*)d_in[6];
    const float* a0W = (const float*)d_in[7],  *a0b = (const float*)d_in[8];
    const float* f0W = (const float*)d_in[9],  *f0b = (const float*)d_in[10];
    const float* g0W = (const float*)d_in[11], *g0b = (const float*)d_in[12];
    const float* a1W = (const float*)d_in[13], *a1b = (const float*)d_in[14];
    const float* f1W = (const float*)d_in[15], *f1b = (const float*)d_in[16];
    const float* g1W = (const float*)d_in[17], *g1b = (const float*)d_in[18];
    const float* a2W = (const float*)d_in[19], *a2b = (const float*)d_in[20];
    const float* f2W = (const float*)d_in[21], *f2b = (const float*)d_in[22];
    const float* g2W = (const float*)d_in[23], *g2b = (const float*)d_in[24];
    const float* o1W = (const float*)d_in[25], *o1b = (const float*)d_in[26];
    const float* o2W = (const float*)d_in[27], *o2b = (const float*)d_in[28];
    float* outp = (float*)d_out;

    char* p = (char*)d_ws;
    auto alloc = [&](size_t bytes) {
        char* r = p;
        p += (bytes + 255) & ~(size_t)255;
        return r;
    };
    float* dinv = (float*)alloc((size_t)N_NODES * 4);
    int* degc   = (int*)alloc((size_t)N_NODES * 4);
    int* offs   = (int*)alloc((size_t)(N_NODES + 1) * 4);
    int* csr    = (int*)alloc((size_t)N_EDGES * 4);
    int* bsums  = (int*)alloc(256 * 4);
    float* g    = (float*)alloc((size_t)B_GRAPH * 256 * 4);
    float* AF   = (float*)alloc((size_t)B_GRAPH * NH * 512 * 4);
    unsigned short* xw1b = (unsigned short*)alloc((size_t)N_NODES * 256 * 2);  // bf16
    unsigned short* x1b  = (unsigned short*)alloc((size_t)N_NODES * 256 * 2);  // bf16 (host rows)
    float* xw2  = (float*)alloc((size_t)N_NODES * 64 * 4);
    uint4* w1h  = (uint4*)alloc((size_t)2048 * 16);  // W1 hi frags (16 cfrag x 2 ks x 64)
    uint4* w1l  = (uint4*)alloc((size_t)2048 * 16);
    uint4* w2h  = (uint4*)alloc((size_t)2048 * 16);  // W2 hi frags (4 cfrag x 8 ks x 64)
    uint4* w2l  = (uint4*)alloc((size_t)2048 * 16);

    size_t need = (size_t)(p - (char*)d_ws);
    if (need > ws_size) {
        fprintf(stderr, "kernel_launch: ws too small (%zu needed, %zu have)\n", need, ws_size);
        return;
    }

    (void)hipMemsetAsync(degc, 0, (size_t)N_NODES * 4, stream);
    // degree count (per-node atomics) | W1/W2 hi-lo fragment prep
    count_deg<<<1616, 256, 0, stream>>>(ei32, ei64, degc, W1, W2, w1h, w1l, w2h, w2l);
    scan_block_sums<<<200, 256, 0, stream>>>(degc, bsums);
    scan_finalize<<<200, 256, 0, stream>>>(degc, offs, dinv, bsums);

    // af0 first | csr-fill/gemm1-MFMA interleaved by parity (XCD-grouped cols)
    fused_gemm1<<<3616, 256, 0, stream>>>(
        x, w1h, w1l, (float*)xw1b, dinv, ei32, ei64, degc, csr,
        hidx, a0W, a0b, f0W, f0b, AF);
    // attn reduce 0 | agg (8 v/block) + fused gemm2 MFMA -> xw2 directly
    fused_agg256<<<256 + 6400, 256, 0, stream>>>((const uint4*)xw1b, dinv, offs, csr,
                                                 b1, (uint4*)x1b, w2h, w2l, xw2,
                                                 AF, g0W, g0b, nullptr, g);
    // af1 only (bf16 host rows of x1b)
    fused_gemm2<<<416, 256, 0, stream>>>(
        (const float*)x1b, hidx, a1W, a1b, f1W, f1b, AF);
    // per-graph (1024 thr): reduce1 + host-only agg + attn2 + g2 update + head
    attn_graph_head<<<256, 1024, 0, stream>>>(
        AF, g1W, g1b, g, xw2, dinv, offs, csr, b2, hidx,
        a2W, a2b, f2W, f2b, g2W, g2b, o1W, o1b, o2W, o2b, outp);
}

// Round 10
// 252.569 us; speedup vs baseline: 1.0112x; 1.0112x over previous
//
#include <hip/hip_runtime.h>
#include <math.h>
#include <stdio.h>

#define N_NODES 51200
#define N_EDGES 409600
#define B_GRAPH 256
#define NH 13

typedef float v4f __attribute__((ext_vector_type(4)));
typedef short s16x8 __attribute__((ext_vector_type(8)));   // 8 bf16 = 4 VGPR (MFMA A/B frag)
typedef float f32x4 __attribute__((ext_vector_type(4)));   // MFMA C/D frag

// bf16 pack (RNE) / unpack helpers.
__device__ __forceinline__ unsigned pack_bf2(float a, float b) {
    unsigned ua = __float_as_uint(a);
    ua = (ua + 0x7fffu + ((ua >> 16) & 1u)) >> 16;
    unsigned ub = __float_as_uint(b);
    ub = (ub + 0x7fffu + ((ub >> 16) & 1u)) & 0xffff0000u;
    return ua | ub;
}
__device__ __forceinline__ float bf_lo(unsigned u) { return __uint_as_float(u << 16); }
__device__ __forceinline__ float bf_hi(unsigned u) { return __uint_as_float(u & 0xffff0000u); }

__device__ __forceinline__ s16x8 as_s8(uint4 u) {
    return __builtin_bit_cast(s16x8, u);
}
__device__ __forceinline__ f32x4 mfma16(s16x8 a, s16x8 b, f32x4 c) {
    return __builtin_amdgcn_mfma_f32_16x16x32_bf16(a, b, c, 0, 0, 0);
}

// Split 8 fp32 (two float4 = frag elems e0..3, e4..7) into hi/lo bf16 frags.
__device__ __forceinline__ void cvt_hilo(const float4& xa, const float4& xb,
                                         s16x8& hi, s16x8& lo) {
    unsigned h0 = pack_bf2(xa.x, xa.y);
    unsigned h1 = pack_bf2(xa.z, xa.w);
    unsigned h2 = pack_bf2(xb.x, xb.y);
    unsigned h3 = pack_bf2(xb.z, xb.w);
    unsigned l0 = pack_bf2(xa.x - bf_lo(h0), xa.y - bf_hi(h0));
    unsigned l1 = pack_bf2(xa.z - bf_lo(h1), xa.w - bf_hi(h1));
    unsigned l2 = pack_bf2(xb.x - bf_lo(h2), xb.y - bf_hi(h2));
    unsigned l3 = pack_bf2(xb.z - bf_lo(h3), xb.w - bf_hi(h3));
    hi = as_s8(make_uint4(h0, h1, h2, h3));
    lo = as_s8(make_uint4(l0, l1, l2, l3));
}

// ei dtype probe, inlined: int64 ei has zero high words (uniform scalar loads).
__device__ __forceinline__ bool ei_is_64(const int* __restrict__ ei32) {
    int z = 1;
    #pragma unroll
    for (int k = 1; k < 16; k += 2) z &= (ei32[k] == 0);
    return z != 0;
}

// count_deg (per-node atomics, 51200 counters -> ~8/addr, uncontended) +
// fused W1/W2 hi/lo MFMA-fragment prep (blocks >= 1600).
__global__ void count_deg(const int* __restrict__ ei32, const long long* __restrict__ ei64,
                          int* __restrict__ degc,
                          const float* __restrict__ W1, const float* __restrict__ W2,
                          uint4* __restrict__ w1h, uint4* __restrict__ w1l,
                          uint4* __restrict__ w2h, uint4* __restrict__ w2l) {
    const int bid = blockIdx.x;
    if (bid >= 1600) {
        int rec = (bid - 1600) * 256 + threadIdx.x;  // [0,4096)
        bool isW1 = rec < 2048;
        int r = isW1 ? rec : rec - 2048;
        int l = r & 63;
        int lg = l >> 4;
        int col, krow, N;
        const float* W;
        if (isW1) {  // 16 cfrag x 2 ks x 64 lanes
            int c = r >> 7; int s = (r >> 6) & 1;
            col = c * 16 + (l & 15); krow = s * 32 + lg * 4; W = W1; N = 256;
        } else {     // 4 cfrag x 8 ks x 64 lanes
            int c = r >> 9; int s = (r >> 6) & 7;
            col = c * 16 + (l & 15); krow = s * 32 + lg * 4; W = W2; N = 64;
        }
        float f[8];
        #pragma unroll
        for (int e = 0; e < 8; ++e) {
            int kk = krow + (e & 3) + 16 * (e >> 2);
            f[e] = W[(size_t)kk * N + col];
        }
        unsigned h[4], lo[4];
        #pragma unroll
        for (int p = 0; p < 4; ++p) {
            h[p] = pack_bf2(f[2 * p], f[2 * p + 1]);
            lo[p] = pack_bf2(f[2 * p] - bf_lo(h[p]), f[2 * p + 1] - bf_hi(h[p]));
        }
        uint4 H = make_uint4(h[0], h[1], h[2], h[3]);
        uint4 L = make_uint4(lo[0], lo[1], lo[2], lo[3]);
        if (isW1) { w1h[r] = H; w1l[r] = L; }
        else      { w2h[r] = H; w2l[r] = L; }
        return;
    }
    int e = bid * 256 + threadIdx.x;
    if (e >= N_EDGES) return;
    int v = ei_is_64(ei32) ? (int)__builtin_nontemporal_load(&ei64[N_EDGES + e])
                           : __builtin_nontemporal_load(&ei32[N_EDGES + e]);
    atomicAdd(&degc[v], 1);
}

__global__ void scan_block_sums(const int* __restrict__ degc, int* __restrict__ bsums) {
    __shared__ int sdata[256];
    int i = blockIdx.x * 256 + threadIdx.x;
    sdata[threadIdx.x] = degc[i];
    __syncthreads();
    for (int s = 128; s > 0; s >>= 1) {
        if (threadIdx.x < s) sdata[threadIdx.x] += sdata[threadIdx.x + s];
        __syncthreads();
    }
    if (threadIdx.x == 0) bsums[blockIdx.x] = sdata[0];
}

__global__ void scan_finalize(int* __restrict__ degc, int* __restrict__ offs,
                              float* __restrict__ dinv, const int* __restrict__ bsums) {
    __shared__ int bs[256];
    __shared__ int s[256];
    const int t = threadIdx.x;
    bs[t] = (t < 200) ? bsums[t] : 0;
    __syncthreads();
    for (int off = 1; off < 256; off <<= 1) {
        int u = (t >= off) ? bs[t - off] : 0;
        __syncthreads();
        bs[t] += u;
        __syncthreads();
    }
    int i = blockIdx.x * 256 + t;
    int cnt = degc[i];
    s[t] = cnt;
    __syncthreads();
    for (int off = 1; off < 256; off <<= 1) {
        int u = (t >= off) ? s[t - off] : 0;
        __syncthreads();
        s[t] += u;
        __syncthreads();
    }
    int base = (blockIdx.x == 0) ? 0 : bs[blockIdx.x - 1];
    int excl = base + s[t] - cnt;
    offs[i] = excl;
    dinv[i] = rsqrtf((float)(cnt + 1));
    degc[i] = excl;  // fill cursor
    if (i == N_NODES - 1) offs[N_NODES] = N_EDGES;
}

// ---- 64x64 tile body (af path): gather + bias, fp32 out, 4x4/thread ----
template <int K, int WS, bool BF16IN>
__device__ __forceinline__ void gemm_body64(const float* __restrict__ X,
        const float* __restrict__ W, const float* __restrict__ bias,
        float* __restrict__ Y, int row0, const int* __restrict__ rows,
        float* __restrict__ xs, float* __restrict__ ws) {
    constexpr int BK = 32;
    constexpr int XS = BK + 4;
    const int t = threadIdx.x;
    const int ct = t & 15;
    const int rt = t >> 4;
    float acc[4][4] = {{0.f}};
    for (int kc = 0; kc < K; kc += BK) {
        __syncthreads();
        #pragma unroll
        for (int i = 0; i < 2; ++i) {
            int idx = t + i * 256;
            int q = idx & 7, r = idx >> 3;
            int xr = rows[r];
            float4 v;
            if (BF16IN) {
                uint2 pv = ((const uint2*)X)[(size_t)xr * (K / 4) + kc / 4 + q];
                v = make_float4(bf_lo(pv.x), bf_hi(pv.x), bf_lo(pv.y), bf_hi(pv.y));
            } else {
                v = *(const float4*)(X + (size_t)xr * K + kc + q * 4);
            }
            *(float4*)&xs[r * XS + q * 4] = v;
        }
        #pragma unroll
        for (int i = 0; i < 2; ++i) {
            int idx = t + i * 256;
            int q = idx & 15, k = idx >> 4;
            float4 v = *(const float4*)(W + (size_t)(kc + k) * WS + q * 4);
            *(float4*)&ws[k * 64 + q * 4] = v;
        }
        __syncthreads();
        #pragma unroll
        for (int kb = 0; kb < BK; kb += 4) {
            float4 wv[4];
            #pragma unroll
            for (int kk = 0; kk < 4; ++kk)
                wv[kk] = *(const float4*)&ws[(kb + kk) * 64 + ct * 4];
            #pragma unroll
            for (int r = 0; r < 4; ++r) {
                float4 xv = *(const float4*)&xs[(rt * 4 + r) * XS + kb];
                float xk[4] = {xv.x, xv.y, xv.z, xv.w};
                #pragma unroll
                for (int kk = 0; kk < 4; ++kk) {
                    acc[r][0] = fmaf(xk[kk], wv[kk].x, acc[r][0]);
                    acc[r][1] = fmaf(xk[kk], wv[kk].y, acc[r][1]);
                    acc[r][2] = fmaf(xk[kk], wv[kk].z, acc[r][2]);
                    acc[r][3] = fmaf(xk[kk], wv[kk].w, acc[r][3]);
                }
            }
        }
    }
    #pragma unroll
    for (int r = 0; r < 4; ++r) {
        int row = row0 + rt * 4 + r;
        float4 o = make_float4(acc[r][0] + bias[ct * 4 + 0],
                               acc[r][1] + bias[ct * 4 + 1],
                               acc[r][2] + bias[ct * 4 + 2],
                               acc[r][3] + bias[ct * 4 + 3]);
        *(float4*)&Y[(size_t)row * 512 + ct * 4] = o;
    }
}

// ---- fused 1: [0,416) af0 (heaviest per-block: start first),
//      [416,3616) csr-fill (even parity) interleaved with gemm1 MFMA (odd). ----
__global__ __launch_bounds__(256, 4) void fused_gemm1(const float* __restrict__ x,
        const uint4* __restrict__ w1h, const uint4* __restrict__ w1l,
        float* __restrict__ xw1b, const float* __restrict__ dinv,
        const int* __restrict__ ei32, const long long* __restrict__ ei64,
        int* __restrict__ cursor, int* __restrict__ csr,
        const int* __restrict__ host_idx,
        const float* __restrict__ a0W, const float* __restrict__ a0b,
        const float* __restrict__ f0W, const float* __restrict__ f0b,
        float* __restrict__ AF) {
    __shared__ float smem[64 * 68];  // af scratch / gemm epilogue
    __shared__ int rows[64];
    const int bid = blockIdx.x;
    const int t = threadIdx.x;
    if (bid < 416) {
        const int rb = bid >> 3;
        const int cb = bid & 7;
        const int c0 = cb * 64;
        const float* Wp = (c0 < 256) ? (a0W + c0) : (f0W + (c0 - 256));
        const float* bp = (c0 < 256) ? (a0b + c0) : (f0b + (c0 - 256));
        if (t < 64) rows[t] = host_idx[rb * 64 + t];
        __syncthreads();
        gemm_body64<64, 256, false>(x, Wp, bp, AF + c0, rb * 64, rows, smem, smem + 64 * 36);
    } else if ((bid - 416) & 1) {
        const int gid = (bid - 416) >> 1;   // [0,1600)
        const int row0 = (gid % 400) * 128;
        const int c0 = (gid / 400) * 64;
        const int w = t >> 6, l = t & 63, lr = l & 15, lg = l >> 4;
        f32x4 acc[2][4] = {};
        #pragma unroll
        for (int s = 0; s < 2; ++s) {
            s16x8 bh[4], bl[4];
            #pragma unroll
            for (int cc = 0; cc < 4; ++cc) {
                int idx = (((c0 >> 4) + cc) * 2 + s) * 64 + l;
                bh[cc] = as_s8(w1h[idx]);
                bl[cc] = as_s8(w1l[idx]);
            }
            #pragma unroll
            for (int f = 0; f < 2; ++f) {
                int rowA = row0 + w * 32 + f * 16 + lr;
                const float* xp = x + (size_t)rowA * 64 + s * 32 + lg * 4;
                float4 xa = *(const float4*)xp;
                float4 xb = *(const float4*)(xp + 16);
                s16x8 ah, al;
                cvt_hilo(xa, xb, ah, al);
                #pragma unroll
                for (int cc = 0; cc < 4; ++cc) {
                    acc[f][cc] = mfma16(ah, bh[cc], acc[f][cc]);
                    acc[f][cc] = mfma16(al, bh[cc], acc[f][cc]);
                    acc[f][cc] = mfma16(ah, bl[cc], acc[f][cc]);
                }
            }
        }
        // epilogue: dinv prescale -> LDS transpose (2 slices of 64 rows) -> bf16 store
        #pragma unroll
        for (int f = 0; f < 2; ++f) {
            if (f) __syncthreads();
            #pragma unroll
            for (int r = 0; r < 4; ++r) {
                float dv = dinv[row0 + w * 32 + f * 16 + lg * 4 + r];
                #pragma unroll
                for (int cc = 0; cc < 4; ++cc)
                    smem[(w * 16 + lg * 4 + r) * 68 + cc * 16 + lr] = acc[f][cc][r] * dv;
            }
            __syncthreads();
            int row_l = t >> 2, cB = (t & 3) * 16;
            int grow = row0 + (row_l >> 4) * 32 + f * 16 + (row_l & 15);
            const float* src = &smem[row_l * 68 + cB];
            float4 v0 = *(const float4*)(src + 0);
            float4 v1 = *(const float4*)(src + 4);
            float4 v2 = *(const float4*)(src + 8);
            float4 v3 = *(const float4*)(src + 12);
            uint4 o0, o1;
            o0.x = pack_bf2(v0.x, v0.y); o0.y = pack_bf2(v0.z, v0.w);
            o0.z = pack_bf2(v1.x, v1.y); o0.w = pack_bf2(v1.z, v1.w);
            o1.x = pack_bf2(v2.x, v2.y); o1.y = pack_bf2(v2.z, v2.w);
            o1.z = pack_bf2(v3.x, v3.y); o1.w = pack_bf2(v3.z, v3.w);
            uint4* yp = (uint4*)xw1b + (size_t)grow * 32 + (c0 >> 3) + (t & 3) * 2;
            yp[0] = o0;
            yp[1] = o1;
        }
    } else {
        int e = ((bid - 416) >> 1) * 256 + t;   // [0,1600) blocks
        if (e < N_EDGES) {
            int u, v;
            if (ei_is_64(ei32)) {
                u = (int)__builtin_nontemporal_load(&ei64[e]);
                v = (int)__builtin_nontemporal_load(&ei64[N_EDGES + e]);
            } else {
                u = __builtin_nontemporal_load(&ei32[e]);
                v = __builtin_nontemporal_load(&ei32[N_EDGES + e]);
            }
            int pos = atomicAdd(&cursor[v], 1);
            csr[pos] = u;
        }
    }
}

// ---- fused 2 (af1 only now): 416 blocks, gather host rows of x1b ----
__global__ __launch_bounds__(256, 4) void fused_gemm2(const float* __restrict__ x1b,
        const int* __restrict__ host_idx,
        const float* __restrict__ a1W, const float* __restrict__ a1b,
        const float* __restrict__ f1W, const float* __restrict__ f1b,
        float* __restrict__ AF) {
    __shared__ float smem[64 * 68];
    __shared__ int rows[64];
    const int bid = blockIdx.x;
    const int t = threadIdx.x;
    const int rb = bid >> 3;
    const int cb = bid & 7;
    const int c0 = cb * 64;
    const float* Wp = (c0 < 256) ? (a1W + c0) : (f1W + (c0 - 256));
    const float* bp = (c0 < 256) ? (a1b + c0) : (f1b + (c0 - 256));
    if (t < 64) rows[t] = host_idx[rb * 64 + t];
    __syncthreads();
    gemm_body64<256, 256, true>(x1b, Wp, bp, AF + c0, rb * 64, rows, smem, smem + 64 * 36);
}

// ---- attn reduce body (H=256): softmax over feats + weighted sum + g update ----
__device__ __forceinline__ void attn_red256(const float* __restrict__ AF,
        const float* __restrict__ gW, const float* __restrict__ gb,
        const float* __restrict__ g_in, float* __restrict__ g_out, int b,
        float (*At)[256], float* red_m, float* red_s, float* cat) {
    const int t = threadIdx.x;
    const int wave = t >> 6, lane = t & 63;
    float accA[NH], accF[NH];
    #pragma unroll
    for (int j = 0; j < NH; ++j) {
        const float* r = AF + (size_t)(b * NH + j) * 512;
        accA[j] = r[t];
        accF[j] = r[256 + t];
        At[j][t] = accA[j];
    }
    __syncthreads();
    for (int j = wave; j < NH; j += 4) {
        float m = -3.402823466e38f;
        #pragma unroll
        for (int q = 0; q < 4; ++q) m = fmaxf(m, At[j][q * 64 + lane]);
        #pragma unroll
        for (int off = 32; off; off >>= 1) m = fmaxf(m, __shfl_xor(m, off));
        if (lane == 0) red_m[j] = m;
    }
    __syncthreads();
    #pragma unroll
    for (int j = 0; j < NH; ++j) At[j][t] = expf(accA[j] - red_m[j]);
    __syncthreads();
    for (int j = wave; j < NH; j += 4) {
        float s = 0.f;
        #pragma unroll
        for (int q = 0; q < 4; ++q) s += At[j][q * 64 + lane];
        #pragma unroll
        for (int off = 32; off; off >>= 1) s += __shfl_xor(s, off);
        if (lane == 0) red_s[j] = s;
    }
    __syncthreads();
    float outc = 0.f;
    #pragma unroll
    for (int j = 0; j < NH; ++j) outc += At[j][t] / red_s[j] * accF[j];
    cat[t] = outc;
    float gv = g_in ? g_in[b * 256 + t] : 0.f;
    cat[256 + t] = gv;
    __syncthreads();
    float acc = gb[t];
    const float* gwp = gW + t;
    #pragma unroll 4
    for (int i4 = 0; i4 < 128; ++i4) {
        float4 cq = ((const float4*)cat)[i4];
        const float* gw4 = gwp + (size_t)i4 * 4 * 256;
        acc = fmaf(cq.x, gw4[0], acc);
        acc = fmaf(cq.y, gw4[256], acc);
        acc = fmaf(cq.z, gw4[512], acc);
        acc = fmaf(cq.w, gw4[768], acc);
    }
    g_out[b * 256 + t] = gv + acc;
}

// ---- fused: [0,256) attn reduce 0, [256,3456) agg_max + FUSED gemm2:
//      block handles 16 v; half-wave hw gathers v0+hw*2(+1) full-row
//      (round-6 pattern, 8 uint4 in flight); relu'd bf16 rows -> LDS
//      (stride 132 uints, pad kills bank conflicts); host rows also -> x1b.
//      Then 4 waves compute xw2[16 rows][16 cols each] via MFMA w2 hi/lo. ----
__global__ __launch_bounds__(256) void fused_agg256(const uint4* __restrict__ xwb4,
        const float* __restrict__ dinv, const int* __restrict__ offs,
        const int* __restrict__ csr, const float* __restrict__ bias,
        uint4* __restrict__ x1b_host,
        const uint4* __restrict__ w2h, const uint4* __restrict__ w2l,
        float* __restrict__ xw2,
        const float* __restrict__ AF, const float* __restrict__ gW,
        const float* __restrict__ gb, const float* __restrict__ g_in,
        float* __restrict__ g_out) {
    __shared__ __align__(16) float At[NH][256];   // 13312 B; gather path overlays x1s
    __shared__ float red_m[NH];
    __shared__ float red_s[NH];
    __shared__ float cat[512];
    const int bid = blockIdx.x;
    if (bid < 256) {
        attn_red256(AF, gW, gb, g_in, g_out, bid, At, red_m, red_s, cat);
        return;
    }
    unsigned* x1s = (unsigned*)At;              // [16][132] uints (8448 B)
    const int t = threadIdx.x;
    const int v0 = (bid - 256) * 16;
    const int hw = t >> 5;                      // half-wave 0..7
    const int cl = t & 31;                      // uint4 chunk in row
    #pragma unroll
    for (int vi = 0; vi < 2; ++vi) {
        const int v = v0 + hw * 2 + vi;
        uint4 sw = xwb4[(size_t)v * 32 + cl];   // self row (pre-scaled bf16)
        float acc[8];
        acc[0] = bf_lo(sw.x); acc[1] = bf_hi(sw.x);
        acc[2] = bf_lo(sw.y); acc[3] = bf_hi(sw.y);
        acc[4] = bf_lo(sw.z); acc[5] = bf_hi(sw.z);
        acc[6] = bf_lo(sw.w); acc[7] = bf_hi(sw.w);
        const int e0 = offs[v];
        const int e1 = offs[v + 1];
        const int em = e0 + ((e1 - e0) & ~7);
        for (int e = e0; e < em; e += 8) {      // 8 edges in flight
            int u[8];
            #pragma unroll
            for (int i = 0; i < 8; ++i) u[i] = csr[e + i];
            uint4 m[8];
            #pragma unroll
            for (int i = 0; i < 8; ++i) m[i] = xwb4[(size_t)u[i] * 32 + cl];
            #pragma unroll
            for (int i = 0; i < 8; ++i) {
                acc[0] = fmaxf(acc[0], bf_lo(m[i].x)); acc[1] = fmaxf(acc[1], bf_hi(m[i].x));
                acc[2] = fmaxf(acc[2], bf_lo(m[i].y)); acc[3] = fmaxf(acc[3], bf_hi(m[i].y));
                acc[4] = fmaxf(acc[4], bf_lo(m[i].z)); acc[5] = fmaxf(acc[5], bf_hi(m[i].z));
                acc[6] = fmaxf(acc[6], bf_lo(m[i].w)); acc[7] = fmaxf(acc[7], bf_hi(m[i].w));
            }
        }
        if (em < e1) {                          // tail <8 edges, clamped
            int u[8];
            #pragma unroll
            for (int i = 0; i < 8; ++i) {
                int idx = em + i;
                u[i] = csr[(idx < e1) ? idx : (e1 - 1)];
            }
            uint4 m[8];
            #pragma unroll
            for (int i = 0; i < 8; ++i) m[i] = xwb4[(size_t)u[i] * 32 + cl];
            #pragma unroll
            for (int i = 0; i < 8; ++i) {
                acc[0] = fmaxf(acc[0], bf_lo(m[i].x)); acc[1] = fmaxf(acc[1], bf_hi(m[i].x));
                acc[2] = fmaxf(acc[2], bf_lo(m[i].y)); acc[3] = fmaxf(acc[3], bf_hi(m[i].y));
                acc[4] = fmaxf(acc[4], bf_lo(m[i].z)); acc[5] = fmaxf(acc[5], bf_hi(m[i].z));
                acc[6] = fmaxf(acc[6], bf_lo(m[i].w)); acc[7] = fmaxf(acc[7], bf_hi(m[i].w));
            }
        }
        float dv = dinv[v];
        float4 ba = ((const float4*)bias)[cl * 2];
        float4 bb = ((const float4*)bias)[cl * 2 + 1];
        uint4 pk;
        pk.x = pack_bf2(fmaxf(fmaf(acc[0], dv, ba.x), 0.f),
                        fmaxf(fmaf(acc[1], dv, ba.y), 0.f));
        pk.y = pack_bf2(fmaxf(fmaf(acc[2], dv, ba.z), 0.f),
                        fmaxf(fmaf(acc[3], dv, ba.w), 0.f));
        pk.z = pack_bf2(fmaxf(fmaf(acc[4], dv, bb.x), 0.f),
                        fmaxf(fmaf(acc[5], dv, bb.y), 0.f));
        pk.w = pack_bf2(fmaxf(fmaf(acc[6], dv, bb.z), 0.f),
                        fmaxf(fmaf(acc[7], dv, bb.w), 0.f));
        int r = hw * 2 + vi;
        *(uint4*)&x1s[r * 132 + cl * 4] = pk;   // LDS row for MFMA phase
        if (v % 200 < NH)                       // host row -> af1 input
            x1b_host[(size_t)v * 32 + cl] = pk;
    }
    __syncthreads();
    // MFMA phase: wave wv computes cols [wv*16, wv*16+16) of xw2 for 16 rows.
    {
        const int wv = t >> 6, l = t & 63;
        const int ra = l & 15, lg = l >> 4;
        f32x4 acc2 = {};
        #pragma unroll
        for (int s = 0; s < 8; ++s) {
            s16x8 bh = as_s8(((const uint4*)w2h)[(wv * 8 + s) * 64 + l]);
            s16x8 bl = as_s8(((const uint4*)w2l)[(wv * 8 + s) * 64 + l]);
            const unsigned* ap = &x1s[ra * 132 + s * 16 + lg * 2];
            s16x8 a = as_s8(make_uint4(ap[0], ap[1], ap[8], ap[9]));
            acc2 = mfma16(a, bh, acc2);
            acc2 = mfma16(a, bl, acc2);
        }
        #pragma unroll
        for (int e = 0; e < 4; ++e) {
            int row = lg * 4 + e;
            xw2[(size_t)(v0 + row) * 64 + wv * 16 + ra] = acc2[e] * dinv[v0 + row];
        }
    }
}

// ---- per-graph mega-kernel, 1024 threads (verified round 13) ----
__global__ __launch_bounds__(1024) void attn_graph_head(
        const float* __restrict__ AF,
        const float* __restrict__ g1W, const float* __restrict__ g1b,
        const float* __restrict__ g_in,
        const float* __restrict__ xw2,
        const float* __restrict__ dinv, const int* __restrict__ offs,
        const int* __restrict__ csr, const float* __restrict__ b2,
        const int* __restrict__ host_idx,
        const float* __restrict__ a2W, const float* __restrict__ a2b,
        const float* __restrict__ f2W, const float* __restrict__ f2b,
        const float* __restrict__ g2W, const float* __restrict__ g2b,
        const float* __restrict__ o1W, const float* __restrict__ o1b,
        const float* __restrict__ o2W, const float* __restrict__ o2b,
        float* __restrict__ out) {
    __shared__ float At[NH][256];
    __shared__ float Ft[NH][256];
    __shared__ float red_m[NH];
    __shared__ float red_s[NH];
    __shared__ float cat[512];
    __shared__ float catB[320];
    __shared__ float g1s[256];
    __shared__ float x2l[NH][64];
    __shared__ float part4[4][256];
    __shared__ float part16[16][64];
    __shared__ float grow[256];
    const int b = blockIdx.x;
    const int t = threadIdx.x;
    const int wave = t >> 6;
    const int lane = t & 63;
    const int c = t & 255;
    const int quad = t >> 8;

    if (wave < NH) {
        int hv = host_idx[b * NH + wave];
        float acc = xw2[(size_t)hv * 64 + lane];
        int e0 = offs[hv], e1 = offs[hv + 1];
        for (int e = e0; e < e1; e += 8) {
            int u[8];
            #pragma unroll
            for (int i = 0; i < 8; ++i) u[i] = csr[(e + i < e1) ? (e + i) : (e1 - 1)];
            float m[8];
            #pragma unroll
            for (int i = 0; i < 8; ++i) m[i] = xw2[(size_t)u[i] * 64 + lane];
            #pragma unroll
            for (int i = 0; i < 8; ++i)
                if (e + i < e1) acc = fmaxf(acc, m[i]);
        }
        x2l[wave][lane] = fmaxf(fmaf(acc, dinv[hv], b2[lane]), 0.f);
    }
    for (int idx = t; idx < NH * 128; idx += 1024) {
        int j = idx >> 7, q = idx & 127;
        float4 v = ((const float4*)(AF + (size_t)(b * NH + j) * 512))[q];
        if (q < 64) *(float4*)&At[j][q * 4] = v;
        else        *(float4*)&Ft[j][(q - 64) * 4] = v;
    }
    __syncthreads();
    if (wave < NH) {
        float m = -3.402823466e38f;
        #pragma unroll
        for (int q = 0; q < 4; ++q) m = fmaxf(m, At[wave][q * 64 + lane]);
        #pragma unroll
        for (int off = 32; off; off >>= 1) m = fmaxf(m, __shfl_xor(m, off));
        if (lane == 0) red_m[wave] = m;
    }
    __syncthreads();
    for (int idx = t; idx < NH * 256; idx += 1024) {
        int j = idx >> 8, cc = idx & 255;
        At[j][cc] = expf(At[j][cc] - red_m[j]);
    }
    __syncthreads();
    if (wave < NH) {
        float s = 0.f;
        #pragma unroll
        for (int q = 0; q < 4; ++q) s += At[wave][q * 64 + lane];
        #pragma unroll
        for (int off = 32; off; off >>= 1) s += __shfl_xor(s, off);
        if (lane == 0) red_s[wave] = s;
    }
    __syncthreads();
    if (quad == 0) {
        float outc = 0.f;
        #pragma unroll
        for (int j = 0; j < NH; ++j) outc += At[j][c] / red_s[j] * Ft[j][c];
        cat[c] = outc;
        cat[256 + c] = g_in[b * 256 + c];
    }
    __syncthreads();
    // g1W update: 512 floats = 128 float4, 32 per quad (full coverage)
    {
        float acc = 0.f;
        const float* gwp = g1W + c;
        #pragma unroll 4
        for (int i4 = quad * 32; i4 < quad * 32 + 32; ++i4) {
            float4 cq = ((const float4*)cat)[i4];
            const float* gw4 = gwp + (size_t)i4 * 1024;
            acc = fmaf(cq.x, gw4[0], acc);
            acc = fmaf(cq.y, gw4[256], acc);
            acc = fmaf(cq.z, gw4[512], acc);
            acc = fmaf(cq.w, gw4[768], acc);
        }
        part4[quad][c] = acc;
    }
    __syncthreads();
    if (quad == 0)
        g1s[c] = cat[256 + c] + g1b[c] +
                 part4[0][c] + part4[1][c] + part4[2][c] + part4[3][c];
    __syncthreads();
    if (wave < NH) {
        float aA = a2b[lane], aF = f2b[lane];
        #pragma unroll 8
        for (int k = 0; k < 64; ++k) {
            float xv = x2l[wave][k];
            aA = fmaf(xv, a2W[k * 64 + lane], aA);
            aF = fmaf(xv, f2W[k * 64 + lane], aF);
        }
        float m = aA;
        #pragma unroll
        for (int off = 32; off; off >>= 1) m = fmaxf(m, __shfl_xor(m, off));
        float pexp = expf(aA - m);
        float s = pexp;
        #pragma unroll
        for (int off = 32; off; off >>= 1) s += __shfl_xor(s, off);
        At[wave][lane] = pexp / s * aF;
    }
    __syncthreads();
    if (t < 64) {
        float o = 0.f;
        #pragma unroll
        for (int j = 0; j < NH; ++j) o += At[j][t];
        catB[t] = o;
    }
    if (quad == 0) catB[64 + c] = g1s[c];
    __syncthreads();
    // g2W update: 320 floats = 80 float4, 20 per quad
    {
        float acc = 0.f;
        const float* gwp = g2W + c;
        #pragma unroll 4
        for (int i4 = quad * 20; i4 < quad * 20 + 20; ++i4) {
            float4 cq = ((const float4*)catB)[i4];
            const float* gw4 = gwp + (size_t)i4 * 1024;
            acc = fmaf(cq.x, gw4[0], acc);
            acc = fmaf(cq.y, gw4[256], acc);
            acc = fmaf(cq.z, gw4[512], acc);
            acc = fmaf(cq.w, gw4[768], acc);
        }
        part4[quad][c] = acc;
    }
    __syncthreads();
    if (quad == 0)
        grow[c] = g1s[c] + g2b[c] +
                  part4[0][c] + part4[1][c] + part4[2][c] + part4[3][c];
    __syncthreads();
    {
        float hp = 0.f;
        #pragma unroll
        for (int k = wave * 16; k < wave * 16 + 16; ++k)
            hp = fmaf(grow[k], o1W[(size_t)k * 64 + lane], hp);
        part16[wave][lane] = hp;
    }
    __syncthreads();
    if (wave == 0) {
        float h = o1b[lane];
        #pragma unroll
        for (int w = 0; w < 16; ++w) h += part16[w][lane];
        h = fmaxf(h, 0.f);
        float sres = h * o2W[lane];
        #pragma unroll
        for (int off = 32; off; off >>= 1) sres += __shfl_xor(sres, off);
        if (lane == 0) out[b] = sres + o2b[0];
    }
}

extern "C" void kernel_launch(void* const* d_in, const int* in_sizes, int n_in,
                              void* d_out, int out_size, void* d_ws, size_t ws_size,
                              hipStream_t stream) {
    (void)in_sizes; (void)n_in; (void)out_size;
    const float* x    = (const float*)d_in[0];
    const int* ei32   = (const int*)d_in[1];
    const long long* ei64 = (const long long*)d_in[1];
    const int* hidx   = (const int*)d_in[2];
    const float* W1 = (const float*)d_in[3],  *b1 = (const float*)d_in[4];
    const float* W2 = (const float*)d_in[5],  *b2 = (const float*)d_in[6];
    const float* a0W = (const float*)d_in[7],  *a0b = (const float*)d_in[8];
    const float* f0W = (const float*)d_in[9],  *f0b = (const float*)d_in[10];
    const float* g0W = (const float*)d_in[11], *g0b = (const float*)d_in[12];
    const float* a1W = (const float*)d_in[13], *a1b = (const float*)d_in[14];
    const float* f1W = (const float*)d_in[15], *f1b = (const float*)d_in[16];
    const float* g1W = (const float*)d_in[17], *g1b = (const float*)d_in[18];
    const float* a2W = (const float*)d_in[19], *a2b = (const float*)d_in[20];
    const float* f2W = (const float*)d_in[21], *f2b = (const float*)d_in[22];
    const float* g2W = (const float*)d_in[23], *g2b = (const float*)d_in[24];
    const float* o1W = (const float*)d_in[25], *o1b = (const float*)d_in[26];
    const float* o2W = (const float*)d_in[27], *o2b = (const float*)d_in[28];
    float* outp = (float*)d_out;

    char* p = (char*)d_ws;
    auto alloc = [&](size_t bytes) {
        char* r = p;
        p += (bytes + 255) & ~(size_t)255;
        return r;
    };
    float* dinv = (float*)alloc((size_t)N_NODES * 4);
    int* degc   = (int*)alloc((size_t)N_NODES * 4);
    int* offs   = (int*)alloc((size_t)(N_NODES + 1) * 4);
    int* csr    = (int*)alloc((size_t)N_EDGES * 4);
    int* bsums  = (int*)alloc(256 * 4);
    float* g    = (float*)alloc((size_t)B_GRAPH * 256 * 4);
    float* AF   = (float*)alloc((size_t)B_GRAPH * NH * 512 * 4);
    unsigned short* xw1b = (unsigned short*)alloc((size_t)N_NODES * 256 * 2);  // bf16
    unsigned short* x1b  = (unsigned short*)alloc((size_t)N_NODES * 256 * 2);  // bf16 (host rows)
    float* xw2  = (float*)alloc((size_t)N_NODES * 64 * 4);
    uint4* w1h  = (uint4*)alloc((size_t)2048 * 16);  // W1 hi frags (16 cfrag x 2 ks x 64)
    uint4* w1l  = (uint4*)alloc((size_t)2048 * 16);
    uint4* w2h  = (uint4*)alloc((size_t)2048 * 16);  // W2 hi frags (4 cfrag x 8 ks x 64)
    uint4* w2l  = (uint4*)alloc((size_t)2048 * 16);

    size_t need = (size_t)(p - (char*)d_ws);
    if (need > ws_size) {
        fprintf(stderr, "kernel_launch: ws too small (%zu needed, %zu have)\n", need, ws_size);
        return;
    }

    (void)hipMemsetAsync(degc, 0, (size_t)N_NODES * 4, stream);
    // degree count (per-node atomics) | W1/W2 hi-lo fragment prep
    count_deg<<<1616, 256, 0, stream>>>(ei32, ei64, degc, W1, W2, w1h, w1l, w2h, w2l);
    scan_block_sums<<<200, 256, 0, stream>>>(degc, bsums);
    scan_finalize<<<200, 256, 0, stream>>>(degc, offs, dinv, bsums);

    // af0 first | csr-fill/gemm1-MFMA interleaved by parity (XCD-grouped cols)
    fused_gemm1<<<3616, 256, 0, stream>>>(
        x, w1h, w1l, (float*)xw1b, dinv, ei32, ei64, degc, csr,
        hidx, a0W, a0b, f0W, f0b, AF);
    // attn reduce 0 | agg (16 v/block) + fused gemm2 MFMA -> xw2 directly
    fused_agg256<<<256 + 3200, 256, 0, stream>>>((const uint4*)xw1b, dinv, offs, csr,
                                                 b1, (uint4*)x1b, w2h, w2l, xw2,
                                                 AF, g0W, g0b, nullptr, g);
    // af1 only (bf16 host rows of x1b)
    fused_gemm2<<<416, 256, 0, stream>>>(
        (const float*)x1b, hidx, a1W, a1b, f1W, f1b, AF);
    // per-graph (1024 thr): reduce1 + host-only agg + attn2 + g2 update + head
    attn_graph_head<<<256, 1024, 0, stream>>>(
        AF, g1W, g1b, g, xw2, dinv, offs, csr, b2, hidx,
        a2W, a2b, f2W, f2b, g2W, g2b, o1W, o1b, o2W, o2b, outp);
}